// Round 15
// baseline (2002.812 us; speedup 1.0000x reference)
//
#include <hip/hip_runtime.h>

typedef _Float16 f16;
typedef _Float16 f16x8 __attribute__((ext_vector_type(8)));
typedef float f32x4 __attribute__((ext_vector_type(4)));

// async global->LDS, 16B per lane; LDS dest must be linear (base + lane*16).
__device__ __forceinline__ void gload_lds16(const void* g, void* l) {
  __builtin_amdgcn_global_load_lds(
      (const __attribute__((address_space(1))) void*)g,
      (__attribute__((address_space(3))) void*)l, 16, 0, 0);
}

__device__ __forceinline__ float act_apply(float x, int id) {
  switch (id) {
    case 0: return fmaxf(x, 0.0f);
    case 1: return 1.0f / (1.0f + __expf(-x));
    case 2: return tanhf(x);
    case 3: return x >= 0.0f ? x : 0.1f * x;
    default: return 1.0507009873554805f *
                    (x > 0.0f ? x : 1.6732632423543772f * expm1f(x));
  }
}

// ============================================================================
// gemm128r: r14 geometry, but 3-slot LDS ring + counted vmcnt(4) instead of
// the per-step vmcnt(0) drain. 48KB LDS -> 3 blocks/CU. One barrier/step.
// Hazards: stage slot (t+2)%3 == (t-1)%3 (freed at step t-1's barrier);
// reads of slot t gated by vmcnt(4)+barrier (only tile t+2 outstanding).
// ============================================================================
__global__ __launch_bounds__(256, 3)
void gemm128r(const f16* __restrict__ A, const f16* __restrict__ W,
              const float* __restrict__ bias, const int* __restrict__ ids,
              float Sa, float invSn, f16* __restrict__ outp,
              int M, int N, int K) {
  __shared__ f16 rA[3][4096];   // 3 x 8 KiB
  __shared__ f16 rB[3][4096];   // 3 x 8 KiB  (48 KiB total)

  const int tid  = (int)threadIdx.x;
  const int lane = tid & 63;
  const int wid  = tid >> 6;
  const int wr   = (wid >> 1) * 64;
  const int wc   = (wid & 1) * 64;

  const int nbc = N >> 7;
  const int b   = (int)blockIdx.x;
  const int x   = b & 7;
  const int r   = b >> 3;
  int brow, bcol;
  if (nbc >= 32) {
    brow = ((x >> 1) * 16 + (r & 15)) << 7;
    bcol = ((x & 1) * (nbc >> 1) + (r >> 4)) << 7;
  } else {
    brow = (x * 8 + (r & 7)) << 7;
    bcol = (r >> 3) << 7;
  }

  const int d0 = tid << 4;
  const int d1 = d0 + 4096;
  const int s0 = d0 ^ (((d0 >> 7) & 7) << 4);
  const int s1 = d1 ^ (((d1 >> 7) & 7) << 4);
  const int r0 = s0 >> 6, c0 = (s0 >> 4) & 3;
  const int r1 = s1 >> 6, c1 = (s1 >> 4) & 3;

  const f16* pA0 = A + (long)(brow + r0) * K + c0 * 8;
  const f16* pA1 = A + (long)(brow + r1) * K + c1 * 8;
  const f16* pB0 = W + (long)(bcol + r0) * K + c0 * 8;
  const f16* pB1 = W + (long)(bcol + r1) * K + c1 * 8;
  const int e0 = tid << 3;
  const int e1 = e0 + 2048;

  const int fr = lane & 15;
  const int kb = lane >> 4;
  const int xorv = ((fr >> 1) & 7) << 4;

  int offA[4], offB[4];
#pragma unroll
  for (int m = 0; m < 4; ++m)
    offA[m] = (((wr + m * 16 + fr) << 6) + (kb << 4)) ^ xorv;
#pragma unroll
  for (int n = 0; n < 4; ++n)
    offB[n] = (((wc + n * 16 + fr) << 6) + (kb << 4)) ^ xorv;

  f32x4 acc[4][4];
#pragma unroll
  for (int m = 0; m < 4; ++m)
#pragma unroll
    for (int n = 0; n < 4; ++n) acc[m][n] = (f32x4){0.f, 0.f, 0.f, 0.f};

  const int nt = K >> 5;

#define RSTAGE(T)                               \
  do {                                          \
    const int _sl = (T) % 3;                    \
    const long _k = (long)(T) << 5;             \
    gload_lds16(pA0 + _k, &rA[_sl][e0]);        \
    gload_lds16(pA1 + _k, &rA[_sl][e1]);        \
    gload_lds16(pB0 + _k, &rB[_sl][e0]);        \
    gload_lds16(pB1 + _k, &rB[_sl][e1]);        \
  } while (0)

  // prologue: tiles 0,1 staged; gate tile 0 (tile 1's 4 loads may stay out)
  RSTAGE(0);
  RSTAGE(1);
  asm volatile("s_waitcnt vmcnt(4)" ::: "memory");
  __builtin_amdgcn_s_barrier();
  asm volatile("" ::: "memory");

  for (int t = 0; t < nt; ++t) {
    if (t + 2 < nt) RSTAGE(t + 2);   // into slot (t-1)%3, freed at t-1's bar

    const int sl = t % 3;
    const char* bA = (const char*)&rA[sl][0];
    const char* bB = (const char*)&rB[sl][0];
    f16x8 af[4], bf[4];
#pragma unroll
    for (int m = 0; m < 4; ++m) af[m] = *(const f16x8*)(bA + offA[m]);
#pragma unroll
    for (int n = 0; n < 4; ++n) bf[n] = *(const f16x8*)(bB + offB[n]);
#pragma unroll
    for (int m = 0; m < 4; ++m)
#pragma unroll
      for (int n = 0; n < 4; ++n)
        acc[m][n] = __builtin_amdgcn_mfma_f32_16x16x32_f16(af[m], bf[n],
                                                           acc[m][n], 0, 0, 0);
    if (t + 1 < nt) {
      // tile t+1 must be landed block-wide; only tile t+2 may stay in flight.
      if (t + 2 < nt) asm volatile("s_waitcnt vmcnt(4)" ::: "memory");
      else            asm volatile("s_waitcnt vmcnt(0)" ::: "memory");
      __builtin_amdgcn_s_barrier();
      asm volatile("" ::: "memory");
    }
  }
#undef RSTAGE

  // sigma-swizzled LDS-transpose epilogue (r10-verified, 0 conflicts)
  __syncthreads();
  char* eb = (char*)&rA[0][0] + wid * 8192;   // 4 x 8KB within the 48KB
  const int r4 = (lane >> 4) << 2;
#pragma unroll
  for (int n = 0; n < 4; ++n) {
    const int gcol = bcol + wc + n * 16 + fr;
    const float bv = bias[gcol];
    const int id   = ids[gcol];
#pragma unroll
    for (int m = 0; m < 4; ++m)
#pragma unroll
      for (int i = 0; i < 4; ++i) {
        const float y = act_apply(acc[m][n][i] * Sa + bv, id);
        const int w = ((m * 16 + r4 + i) * 64 + n * 16 + fr) * 2;
        *(f16*)(eb + (w ^ (((w >> 7) & 7) << 4))) = (f16)(y * invSn);
      }
  }
  __syncthreads();
#pragma unroll
  for (int j = 0; j < 8; ++j) {
    const int lrow = j * 8 + (lane >> 3);
    const int rd = lrow * 128 + (lane & 7) * 16;
    const f16x8 v = *(const f16x8*)(eb + (rd ^ (((rd >> 7) & 7) << 4)));
    *(f16x8*)&outp[(long)(brow + wr + lrow) * N + bcol + wc + (lane & 7) * 8] = v;
  }
}

// ============================================================================
// gemm128 — control (r14 exact): 2-deep dbuf, __syncthreads drain, 4 blk/CU.
// ============================================================================
template <bool FINAL>
__global__ __launch_bounds__(256, 4)
void gemm128(const f16* __restrict__ A, const f16* __restrict__ W,
             const float* __restrict__ bias, const int* __restrict__ ids,
             float Sa, float invSn, void* __restrict__ outv,
             int M, int N, int K) {
  __shared__ f16 lA[2][128 * 32];
  __shared__ f16 lB[2][128 * 32];

  const int tid  = (int)threadIdx.x;
  const int lane = tid & 63;
  const int wid  = tid >> 6;
  const int wr   = (wid >> 1) * 64;
  const int wc   = (wid & 1) * 64;

  const int nbc = N >> 7;
  const int b   = (int)blockIdx.x;
  const int x   = b & 7;
  const int r   = b >> 3;
  int brow, bcol;
  if (nbc >= 32) {
    brow = ((x >> 1) * 16 + (r & 15)) << 7;
    bcol = ((x & 1) * (nbc >> 1) + (r >> 4)) << 7;
  } else {
    brow = (x * 8 + (r & 7)) << 7;
    bcol = (r >> 3) << 7;
  }

  const int d0 = tid << 4;
  const int d1 = d0 + 4096;
  const int s0 = d0 ^ (((d0 >> 7) & 7) << 4);
  const int s1 = d1 ^ (((d1 >> 7) & 7) << 4);
  const int r0 = s0 >> 6, c0 = (s0 >> 4) & 3;
  const int r1 = s1 >> 6, c1 = (s1 >> 4) & 3;

  const f16* pA0 = A + (long)(brow + r0) * K + c0 * 8;
  const f16* pA1 = A + (long)(brow + r1) * K + c1 * 8;
  const f16* pB0 = W + (long)(bcol + r0) * K + c0 * 8;
  const f16* pB1 = W + (long)(bcol + r1) * K + c1 * 8;
  const int e0 = tid << 3;
  const int e1 = e0 + 2048;

  const int fr = lane & 15;
  const int kb = lane >> 4;
  const int xorv = ((fr >> 1) & 7) << 4;

  int offA[4], offB[4];
#pragma unroll
  for (int m = 0; m < 4; ++m)
    offA[m] = (((wr + m * 16 + fr) << 6) + (kb << 4)) ^ xorv;
#pragma unroll
  for (int n = 0; n < 4; ++n)
    offB[n] = (((wc + n * 16 + fr) << 6) + (kb << 4)) ^ xorv;

  f32x4 acc[4][4];
#pragma unroll
  for (int m = 0; m < 4; ++m)
#pragma unroll
    for (int n = 0; n < 4; ++n) acc[m][n] = (f32x4){0.f, 0.f, 0.f, 0.f};

  const int nt = K >> 5;
  int buf = 0;

  gload_lds16(pA0, &lA[0][e0]);
  gload_lds16(pA1, &lA[0][e1]);
  gload_lds16(pB0, &lB[0][e0]);
  gload_lds16(pB1, &lB[0][e1]);
  __syncthreads();

  for (int t = 0; t < nt; ++t) {
    if (t + 1 < nt) {
      const long kk = (long)(t + 1) << 5;
      gload_lds16(pA0 + kk, &lA[buf ^ 1][e0]);
      gload_lds16(pA1 + kk, &lA[buf ^ 1][e1]);
      gload_lds16(pB0 + kk, &lB[buf ^ 1][e0]);
      gload_lds16(pB1 + kk, &lB[buf ^ 1][e1]);
    }
    const char* bA = (const char*)&lA[buf][0];
    const char* bB = (const char*)&lB[buf][0];
    f16x8 af[4], bf[4];
#pragma unroll
    for (int m = 0; m < 4; ++m) af[m] = *(const f16x8*)(bA + offA[m]);
#pragma unroll
    for (int n = 0; n < 4; ++n) bf[n] = *(const f16x8*)(bB + offB[n]);
#pragma unroll
    for (int m = 0; m < 4; ++m)
#pragma unroll
      for (int n = 0; n < 4; ++n)
        acc[m][n] = __builtin_amdgcn_mfma_f32_16x16x32_f16(af[m], bf[n],
                                                           acc[m][n], 0, 0, 0);
    if (t + 1 < nt) {
      __syncthreads();
      buf ^= 1;
    }
  }

  const int r4 = (lane >> 4) << 2;
  if (!FINAL) {
    __syncthreads();
    char* eb = (char*)((wid < 2) ? &lA[wid][0] : &lB[wid - 2][0]);
#pragma unroll
    for (int n = 0; n < 4; ++n) {
      const int gcol = bcol + wc + n * 16 + fr;
      const float bv = bias[gcol];
      const int id   = ids[gcol];
#pragma unroll
      for (int m = 0; m < 4; ++m)
#pragma unroll
        for (int i = 0; i < 4; ++i) {
          const float y = act_apply(acc[m][n][i] * Sa + bv, id);
          const int w = ((m * 16 + r4 + i) * 64 + n * 16 + fr) * 2;
          *(f16*)(eb + (w ^ (((w >> 7) & 7) << 4))) = (f16)(y * invSn);
        }
    }
    __syncthreads();
    f16* outp = (f16*)outv;
#pragma unroll
    for (int j = 0; j < 8; ++j) {
      const int lrow = j * 8 + (lane >> 3);
      const int rd = lrow * 128 + (lane & 7) * 16;
      const f16x8 v = *(const f16x8*)(eb + (rd ^ (((rd >> 7) & 7) << 4)));
      *(f16x8*)&outp[(long)(brow + wr + lrow) * N + bcol + wc + (lane & 7) * 8] = v;
    }
  } else {
#pragma unroll
    for (int n = 0; n < 4; ++n) {
      const int gcol = bcol + wc + n * 16 + fr;
      const float bv = bias[gcol];
      const int id   = ids[gcol];
#pragma unroll
      for (int m = 0; m < 4; ++m) {
        const int grow = brow + wr + m * 16 + r4;
#pragma unroll
        for (int i = 0; i < 4; ++i) {
          const float y = act_apply(acc[m][n][i] * Sa + bv, id);
          ((float*)outv)[(long)(grow + i) * N + gcol] = y;
        }
      }
    }
  }
}

__global__ void cvt_f32_to_f16(const float* __restrict__ in, f16* __restrict__ out,
                               float scale, int n) {
  int i = ((int)blockIdx.x * 256 + (int)threadIdx.x) * 8;
  const int stride = (int)gridDim.x * 256 * 8;
  for (; i < n; i += stride) {
    const float4 v0 = *(const float4*)(in + i);
    const float4 v1 = *(const float4*)(in + i + 4);
    f16x8 h;
    h[0] = (f16)(v0.x * scale); h[1] = (f16)(v0.y * scale);
    h[2] = (f16)(v0.z * scale); h[3] = (f16)(v0.w * scale);
    h[4] = (f16)(v1.x * scale); h[5] = (f16)(v1.y * scale);
    h[6] = (f16)(v1.z * scale); h[7] = (f16)(v1.w * scale);
    *(f16x8*)(out + i) = h;
  }
}

extern "C" void kernel_launch(void* const* d_in, const int* in_sizes, int n_in,
                              void* d_out, int out_size, void* d_ws, size_t ws_size,
                              hipStream_t stream) {
  (void)in_sizes; (void)n_in; (void)out_size; (void)ws_size;
  const int M = 8192, IND = 2048, HID = 4096, OUTD = 2048;
  const float* x = (const float*)d_in[0];

  f16* actA = (f16*)d_ws;
  f16* actB = actA + (size_t)M * HID;
  f16* wbuf = actB + (size_t)M * HID;

  // static per-layer activation scales (powers of 2, exact)
  const float S[6] = {1.f, 16.f, 512.f, 16384.f, 262144.f, 8388608.f};
  const int Ks[6] = {IND, HID, HID, HID, HID, HID};
  const int Ns[6] = {HID, HID, HID, HID, HID, OUTD};

  cvt_f32_to_f16<<<2048, 256, 0, stream>>>(x, actA, 1.0f, M * IND);

  f16* cur = actA;
  f16* nxt = actB;
  for (int i = 0; i < 6; ++i) {
    const int K = Ks[i], N = Ns[i];
    const float* w  = (const float*)d_in[1 + 3 * i];
    const float* bs = (const float*)d_in[2 + 3 * i];
    const int* id   = (const int*)d_in[3 + 3 * i];

    cvt_f32_to_f16<<<2048, 256, 0, stream>>>(w, wbuf, 1.0f, N * K);

    const int nblk = (M >> 7) * (N >> 7);
    // A/B fork: layers 1,2 -> gemm128r (3-slot ring, counted vmcnt);
    // 0,3,4 -> gemm128 control; 5 -> gemm128<true>.
    // Layers 1,2 vs 3,4 are identical 8192x4096x4096 shapes.
    if (i == 1 || i == 2) {
      gemm128r<<<nblk, 256, 0, stream>>>(
          cur, wbuf, bs, id, S[i], 1.0f / S[i + 1], nxt, M, N, K);
      f16* t = cur; cur = nxt; nxt = t;
    } else if (i < 5) {
      gemm128<false><<<nblk, 256, 0, stream>>>(
          cur, wbuf, bs, id, S[i], 1.0f / S[i + 1], nxt, M, N, K);
      f16* t = cur; cur = nxt; nxt = t;
    } else {
      gemm128<true><<<nblk, 256, 0, stream>>>(
          cur, wbuf, bs, id, S[i], 1.0f, d_out, M, N, K);
    }
  }
}